// Round 1
// baseline (207.120 us; speedup 1.0000x reference)
//
#include <hip/hip_runtime.h>
#include <math.h>

#define HH 96
#define WW 96
#define NPIX (HH*WW)          // 9216
#define CC 320
#define GG 32
#define CPG 10                // channels per group

// ---------------------------------------------------------------------------
// Kernel 1: per (batch, group) sum and sumsq of h = dwconv3x3(x) + dw_b
// grid = 16*32 blocks, 256 threads. Each thread handles float4 pixel chunks.
// ---------------------------------------------------------------------------
__global__ __launch_bounds__(256)
void k_stats(const float* __restrict__ x, const float* __restrict__ dw_w,
             const float* __restrict__ dw_b, float* __restrict__ stats) {
  const int b = blockIdx.x >> 5;   // /32
  const int g = blockIdx.x & 31;
  __shared__ float wsm[CPG * 9];
  __shared__ float bsm[CPG];
  const int tid = threadIdx.x;
  if (tid < CPG * 9) wsm[tid] = dw_w[g * CPG * 9 + tid];
  if (tid < CPG)     bsm[tid] = dw_b[g * CPG + tid];
  __syncthreads();

  const float* xb = x + ((size_t)(b * CC + g * CPG)) * NPIX;
  float s1 = 0.f, s2 = 0.f;
  const int CHUNKS_PER_CH = NPIX / 4;        // 2304 (24 chunks per row)
  const int TOT = CPG * CHUNKS_PER_CH;       // 23040 = 90 * 256 exactly

  for (int chunk = tid; chunk < TOT; chunk += 256) {
    int cl  = chunk / CHUNKS_PER_CH;
    int rem = chunk - cl * CHUNKS_PER_CH;
    int y   = rem / 24;
    int xc  = rem - y * 24;                  // chunk column (4 px per chunk)
    const float* img = xb + cl * NPIX;

    float v[3][6];
    #pragma unroll
    for (int ky = 0; ky < 3; ++ky) {
      int yy = y + ky - 1;
      if (yy >= 0 && yy < HH) {
        const float* row = img + yy * WW + xc * 4;
        float4 m = *(const float4*)row;
        v[ky][1] = m.x; v[ky][2] = m.y; v[ky][3] = m.z; v[ky][4] = m.w;
        v[ky][0] = (xc > 0)  ? row[-1] : 0.f;
        v[ky][5] = (xc < 23) ? row[4]  : 0.f;
      } else {
        v[ky][0] = v[ky][1] = v[ky][2] = v[ky][3] = v[ky][4] = v[ky][5] = 0.f;
      }
    }

    const float* wp  = &wsm[cl * 9];
    const float bias = bsm[cl];
    float h[4];
    #pragma unroll
    for (int j = 0; j < 4; ++j) {
      float hh = bias;
      #pragma unroll
      for (int ky = 0; ky < 3; ++ky)
        #pragma unroll
        for (int kx = 0; kx < 3; ++kx)
          hh = fmaf(wp[ky * 3 + kx], v[ky][j + kx], hh);
      h[j] = hh;
    }
    // tree-sum to keep the dependency chain on s1/s2 short
    s1 += (h[0] + h[1]) + (h[2] + h[3]);
    float q0 = fmaf(h[0], h[0], h[1] * h[1]);
    float q1 = fmaf(h[2], h[2], h[3] * h[3]);
    s2 += q0 + q1;
  }

  // wave reduce (64 lanes) then cross-wave via LDS
  #pragma unroll
  for (int off = 32; off; off >>= 1) {
    s1 += __shfl_down(s1, off);
    s2 += __shfl_down(s2, off);
  }
  __shared__ float r1[4], r2[4];
  if ((tid & 63) == 0) { r1[tid >> 6] = s1; r2[tid >> 6] = s2; }
  __syncthreads();
  if (tid == 0) {
    stats[blockIdx.x * 2]     = r1[0] + r1[1] + r1[2] + r1[3];
    stats[blockIdx.x * 2 + 1] = r2[0] + r2[1] + r2[2] + r2[3];
  }
}

// ---------------------------------------------------------------------------
// Kernel 2: fold GN stats + gn_w/gn_b + proj into per-(b,c) 9-tap weights cw
// and a per-batch scalar bias Bv. grid = 16 blocks, 320 threads (c).
// ---------------------------------------------------------------------------
__global__ __launch_bounds__(320)
void k_coef(const float* __restrict__ stats, const float* __restrict__ dw_w,
            const float* __restrict__ dw_b, const float* __restrict__ gn_w,
            const float* __restrict__ gn_b, const float* __restrict__ proj_w,
            const float* __restrict__ proj_b,
            float* __restrict__ cw, float* __restrict__ Bv) {
  const int b = blockIdx.x;
  const int c = threadIdx.x;            // 0..319
  const int g = c / CPG;
  const float invN = 1.f / (float)(CPG * NPIX);
  float sum   = stats[(b * GG + g) * 2];
  float sumsq = stats[(b * GG + g) * 2 + 1];
  float mean = sum * invN;
  float var  = sumsq * invN - mean * mean;
  float rinv = rsqrtf(var + 1e-5f);
  float a = proj_w[c] * gn_w[c] * rinv;                 // scale on conv output
  // constant term: proj_w*(gn_b - mean*gn_w*rinv) + a*dw_b  (dw bias folded)
  float contrib = fmaf(proj_w[c], gn_b[c] - mean * gn_w[c] * rinv, a * dw_b[c]);
  #pragma unroll
  for (int k = 0; k < 9; ++k)
    cw[((size_t)b * CC + c) * 9 + k] = a * dw_w[c * 9 + k];

  #pragma unroll
  for (int off = 32; off; off >>= 1)
    contrib += __shfl_down(contrib, off);
  __shared__ float part[5];
  if ((c & 63) == 0) part[c >> 6] = contrib;
  __syncthreads();
  if (c == 0) Bv[b] = part[0] + part[1] + part[2] + part[3] + part[4] + proj_b[0];
}

// ---------------------------------------------------------------------------
// Kernel 3: per-pixel g = sum_c sum_k cw[b,c,k] * x[b,c,p+k] + Bv[b]; sigmoid.
// grid = 16 * 12 * 3 blocks; 256 threads = 32x8 pixel tile.
// ---------------------------------------------------------------------------
__global__ __launch_bounds__(256)
void k_proj(const float* __restrict__ x, const float* __restrict__ cw,
            const float* __restrict__ Bv, float* __restrict__ out) {
  const int bid = blockIdx.x;
  const int xt = bid % 3;
  int t = bid / 3;
  const int yt = t % 12;
  const int b  = t / 12;
  const int tx = threadIdx.x & 31;
  const int ty = threadIdx.x >> 5;
  const int X = xt * 32 + tx;
  const int Y = yt * 8 + ty;

  __shared__ float csm[CC * 9];
  for (int i = threadIdx.x; i < CC * 9; i += 256)
    csm[i] = cw[(size_t)b * CC * 9 + i];
  __syncthreads();

  const bool ym = Y > 0, yp = Y < HH - 1, xm = X > 0, xp = X < WW - 1;
  const float* xb = x + (size_t)b * CC * NPIX + Y * WW + X;

  // 9 independent accumulators (one per tap) to break the FMA latency chain
  float a0=0.f,a1=0.f,a2=0.f,a3=0.f,a4=0.f,a5=0.f,a6=0.f,a7=0.f,a8=0.f;
  for (int c = 0; c < CC; ++c) {
    const float* p1 = xb + c * NPIX;
    const float* p0 = p1 - WW;
    const float* p2 = p1 + WW;
    const float* wc = &csm[c * 9];
    float v00 = (ym && xm) ? p0[-1] : 0.f;
    float v01 =  ym        ? p0[0]  : 0.f;
    float v02 = (ym && xp) ? p0[1]  : 0.f;
    float v10 =  xm        ? p1[-1] : 0.f;
    float v11 =              p1[0];
    float v12 =  xp        ? p1[1]  : 0.f;
    float v20 = (yp && xm) ? p2[-1] : 0.f;
    float v21 =  yp        ? p2[0]  : 0.f;
    float v22 = (yp && xp) ? p2[1]  : 0.f;
    a0 = fmaf(wc[0], v00, a0);
    a1 = fmaf(wc[1], v01, a1);
    a2 = fmaf(wc[2], v02, a2);
    a3 = fmaf(wc[3], v10, a3);
    a4 = fmaf(wc[4], v11, a4);
    a5 = fmaf(wc[5], v12, a5);
    a6 = fmaf(wc[6], v20, a6);
    a7 = fmaf(wc[7], v21, a7);
    a8 = fmaf(wc[8], v22, a8);
  }
  float g = ((a0 + a1) + (a2 + a3)) + ((a4 + a5) + (a6 + a7)) + a8 + Bv[b];
  out[(size_t)b * NPIX + Y * WW + X] = 1.f / (1.f + expf(-g));
}

// ---------------------------------------------------------------------------
extern "C" void kernel_launch(void* const* d_in, const int* in_sizes, int n_in,
                              void* d_out, int out_size, void* d_ws, size_t ws_size,
                              hipStream_t stream) {
  const float* x      = (const float*)d_in[0];
  const float* dw_w   = (const float*)d_in[1];
  const float* dw_b   = (const float*)d_in[2];
  const float* gn_w   = (const float*)d_in[3];
  const float* gn_b   = (const float*)d_in[4];
  const float* proj_w = (const float*)d_in[5];
  const float* proj_b = (const float*)d_in[6];
  float* out = (float*)d_out;

  float* stats = (float*)d_ws;                                   // 512*2 f32
  float* cw    = (float*)((char*)d_ws + 4096);                   // 16*320*9 f32
  float* Bv    = (float*)((char*)d_ws + 4096 + (size_t)16*CC*9*4); // 16 f32

  hipLaunchKernelGGL(k_stats, dim3(16 * 32), dim3(256), 0, stream,
                     x, dw_w, dw_b, stats);
  hipLaunchKernelGGL(k_coef, dim3(16), dim3(320), 0, stream,
                     stats, dw_w, dw_b, gn_w, gn_b, proj_w, proj_b, cw, Bv);
  hipLaunchKernelGGL(k_proj, dim3(16 * 12 * 3), dim3(256), 0, stream,
                     x, cw, Bv, out);
}